// Round 7
// baseline (93.940 us; speedup 1.0000x reference)
//
#include <hip/hip_runtime.h>
#include <hip/hip_bf16.h>

#define NROWS 4096
#define DDIM  256
#define EPS   1e-8f
// Normalized rows are scaled by sqrt(2*log2(e)) so the MFMA dot product IS the
// exp2 argument: exp2(<se_i, se_j>) = exp(<e_i,e_j>/T), T = 0.5.
#define SCALE 1.69864944f
#define LN2   0.69314718056f

#define NJ 32          // j-slices (grid.y)
#define JS 256         // cols per slice
#define BT 32          // cols per staged LDS chunk
#define CH (JS / BT)   // 8 chunks per slice
#define NBUF 4         // quad-buffer: prefetch depth 3
// Buffer, fragment-ordered: [cg(2)][ks(8)][lane(64)][8 shorts] = 16 KB
#define BUFSH (2 * 8 * 64 * 8)

typedef __attribute__((ext_vector_type(8))) short short8;
typedef __attribute__((ext_vector_type(4))) float f32x4;

#if __has_builtin(__builtin_amdgcn_exp2f)
#define EXP2F(x) __builtin_amdgcn_exp2f(x)
#else
#define EXP2F(x) exp2f(x)
#endif

#define VMWAIT(N) asm volatile("s_waitcnt vmcnt(" #N ")" ::: "memory")

__device__ __forceinline__ unsigned short f2bf(float x) {
    union { __hip_bfloat16 h; unsigned short u; } c;
    c.h = __float2bfloat16(x);
    return c.u;
}

__device__ __forceinline__ float bf2f(unsigned short u) {
    union { float f; unsigned int i; } c;
    c.i = ((unsigned int)u) << 16;
    return c.f;
}

// ---------------------------------------------------------------------------
// Kernel 1 (fused normalize + positive_sim): one wave owns the PAIR (i, N+i).
// grid = N/4 blocks x 256 threads.
__global__ void prep_kernel(const float* __restrict__ a,
                            const float* __restrict__ b,
                            unsigned short* __restrict__ en,
                            float* __restrict__ S,
                            float* __restrict__ pos, int N) {
    const int wave = threadIdx.x >> 6, lane = threadIdx.x & 63;
    const int row = blockIdx.x * 4 + wave;          // pair index in [0,N)
    const float4 va = reinterpret_cast<const float4*>(a + (size_t)row * DDIM)[lane];
    const float4 vb = reinterpret_cast<const float4*>(b + (size_t)row * DDIM)[lane];
    float ssa = va.x * va.x + va.y * va.y + va.z * va.z + va.w * va.w;
    float ssb = vb.x * vb.x + vb.y * vb.y + vb.z * vb.z + vb.w * vb.w;
    #pragma unroll
    for (int off = 32; off > 0; off >>= 1) {
        ssa += __shfl_xor(ssa, off);
        ssb += __shfl_xor(ssb, off);
    }
    const float inva = SCALE / fmaxf(sqrtf(ssa), EPS * SCALE);
    const float invb = SCALE / fmaxf(sqrtf(ssb), EPS * SCALE);
    ushort4 oa, ob;
    oa.x = f2bf(va.x * inva); oa.y = f2bf(va.y * inva);
    oa.z = f2bf(va.z * inva); oa.w = f2bf(va.w * inva);
    ob.x = f2bf(vb.x * invb); ob.y = f2bf(vb.y * invb);
    ob.z = f2bf(vb.z * invb); ob.w = f2bf(vb.w * invb);
    *reinterpret_cast<ushort4*>(en + (size_t)row * DDIM + lane * 4) = oa;
    *reinterpret_cast<ushort4*>(en + (size_t)(N + row) * DDIM + lane * 4) = ob;
    float d = bf2f(oa.x) * bf2f(ob.x) + bf2f(oa.y) * bf2f(ob.y) +
              bf2f(oa.z) * bf2f(ob.z) + bf2f(oa.w) * bf2f(ob.w);
    #pragma unroll
    for (int off = 32; off > 0; off >>= 1) d += __shfl_xor(d, off);
    if (lane == 0) {
        pos[row] = d * LN2;
        S[row] = 0.0f;
    }
}

// ---------------------------------------------------------------------------
// Kernel 2: masked exp row-sums via MFMA — deep-prefetch pipeline.
// R3 profiling: MfmaUtil 10.5 / VALUBusy 9.8 / Occ 17 / conflicts 0, pipe-sum
// ~8us vs 38us measured -> ~30us of DMA-latency wait (en = 4MB ~ one XCD L2,
// FETCH = 4x en => ~25% of chunk stages miss to HBM; 1 compute phase of cover
// is not enough, and barrier B stalls all 4 waves together).
// Fix: BT=32 chunks, NBUF=4 (same 64KB LDS), stage 3 chunks AHEAD -> ~3
// compute phases (>3.5k cyc) of latency cover. Counted tail vmcnt keeps loads
// in flight across raw s_barriers (no __syncthreads drain).
// t=4 / 256-thr / (256,2) register shape kept (R3-verified: VGPR 120, 0 spill;
// >=4 waves/SIMD is impossible anyway: afrag alone = 128 unified regs).
// grid = (16 i-blocks of 256 rows, NJ j-slices), block = 256 (4 waves).
// MFMA 16x16x32 bf16 verified layouts:
//   A/B operand: elem j of lane l = M[base + (l&15)][ks*32 + (l>>4)*8 + j]
//   C/D:         reg r of lane l  = C[(l>>4)*4 + r][l&15]
__global__ __launch_bounds__(256, 2) void simsum_kernel(
        const short* __restrict__ en,
        float* __restrict__ S) {
    __shared__ short bt[NBUF * BUFSH];
    const int tid = threadIdx.x;
    const int wave = tid >> 6, lane = tid & 63;
    const int lrow = lane & 15, quad = lane >> 4;
    const int i0 = blockIdx.x * 256 + wave * 64;
    const int jb = blockIdx.y * JS;

    // A fragments: 4 row-tiles x K=256, loaded once (128 unified regs).
    short8 afrag[4][8];
    #pragma unroll
    for (int t = 0; t < 4; ++t)
        #pragma unroll
        for (int ks = 0; ks < 8; ++ks)
            afrag[t][ks] = *reinterpret_cast<const short8*>(
                en + (size_t)(i0 + t * 16 + lrow) * DDIM + ks * 32 + quad * 8);

    float rowsum[4][4];
    #pragma unroll
    for (int t = 0; t < 4; ++t)
        #pragma unroll
        for (int r = 0; r < 4; ++r) rowsum[t][r] = 0.0f;

    // Async stage of one 32-col chunk, split across 4 waves: wave w covers
    // cg = w>>1 (16 cols) and k-half (w&1) — 4 global_load_lds each.
    // LDS dest is wave-uniform base + lane*16B == fragment order for ds_read.
    const int scg = wave >> 1, skh = (wave & 1) * 4;
    const short* gbase = en + (size_t)(scg * 16 + lrow) * DDIM + skh * 32 + quad * 8;
    short* lbase = bt + scg * 4096 + skh * 512;
    auto stage = [&](int jc, int buf) {
        const short* g = gbase + (size_t)jc * DDIM;
        short* l = lbase + buf * BUFSH;
        #pragma unroll
        for (int k2 = 0; k2 < 4; ++k2) {
            __builtin_amdgcn_global_load_lds(
                (const __attribute__((address_space(1))) void*)(g + k2 * 32),
                (__attribute__((address_space(3))) void*)(l + k2 * 512),
                16, 0, 0);
        }
    };

    // Prologue: fill the pipeline 3 deep (12 loads/wave in flight).
    stage(jb, 0);
    stage(jb + BT, 1);
    stage(jb + 2 * BT, 2);

    for (int c = 0; c < CH; ++c) {
        // Barrier A: every wave's ds_reads of buffer (c+3)&3 (last read at
        // iter c-1) are delivered (lgkmcnt(0)) -> safe to overwrite.
        asm volatile("s_waitcnt lgkmcnt(0)" ::: "memory");
        __builtin_amdgcn_s_barrier();
        if (c + 3 < CH) {
            stage(jb + (c + 3) * BT, (c + 3) & 3);
            VMWAIT(12);                  // chunk c landed; 3 chunks in flight
        } else if (c + 2 < CH) {
            VMWAIT(8);                   // tail: 2 chunks in flight
        } else if (c + 1 < CH) {
            VMWAIT(4);                   // tail: 1 chunk in flight
        } else {
            VMWAIT(0);                   // final chunk
        }
        __builtin_amdgcn_sched_barrier(0);
        __builtin_amdgcn_s_barrier();    // Barrier B: chunk c visible to all
        const short* lb = bt + (c & 3) * BUFSH;
        #pragma unroll
        for (int cg = 0; cg < 2; ++cg) {
            f32x4 acc[4];
            #pragma unroll
            for (int t = 0; t < 4; ++t) acc[t] = f32x4{0.f, 0.f, 0.f, 0.f};
            __builtin_amdgcn_s_setprio(1);
            #pragma unroll
            for (int ks = 0; ks < 8; ++ks) {
                const short8 bfrag = *reinterpret_cast<const short8*>(
                    lb + cg * 4096 + ks * 512 + lane * 8);
                #pragma unroll
                for (int t = 0; t < 4; ++t)
                    acc[t] = __builtin_amdgcn_mfma_f32_16x16x32_bf16(
                        afrag[t][ks], bfrag, acc[t], 0, 0, 0);
            }
            __builtin_amdgcn_s_setprio(0);
            // Branch-free epilogue: exclude the (at most one) diagonal-family
            // element per lane via compare+select (j%N == i%N).
            const int cm = (jb + c * BT + cg * 16 + lrow) & (NROWS - 1);
            #pragma unroll
            for (int t = 0; t < 4; ++t) {
                const int dd = cm - (i0 + t * 16 + quad * 4);  // match: dd==r
                #pragma unroll
                for (int r = 0; r < 4; ++r) {
                    const float ed = EXP2F(acc[t][r]);
                    rowsum[t][r] += (dd == r) ? 0.0f : ed;
                }
            }
        }
    }

    // Reduce each rowsum over the 16 lanes sharing a quad, then one atomic.
    #pragma unroll
    for (int t = 0; t < 4; ++t) {
        #pragma unroll
        for (int r = 0; r < 4; ++r) {
            float v = rowsum[t][r];
            v += __shfl_xor(v, 1);
            v += __shfl_xor(v, 2);
            v += __shfl_xor(v, 4);
            v += __shfl_xor(v, 8);
            rowsum[t][r] = v;
        }
        if (lrow < 4) {
            const float v = (lrow == 0) ? rowsum[t][0]
                          : (lrow == 1) ? rowsum[t][1]
                          : (lrow == 2) ? rowsum[t][2]
                          :               rowsum[t][3];
            atomicAdd(&S[i0 + t * 16 + quad * 4 + lrow], v);
        }
    }
}

// ---------------------------------------------------------------------------
// Kernel 3: loss = -(1/N) * sum_i (pos[i] - log(S[i])). One block x 1024.
__global__ void loss_kernel(const float* __restrict__ S,
                            const float* __restrict__ pos,
                            float* __restrict__ out, int N) {
    const int i = threadIdx.x * 4;
    float acc = 0.0f;
    if (i < N) {
        const float4 s4 = *reinterpret_cast<const float4*>(S + i);
        const float4 p4 = *reinterpret_cast<const float4*>(pos + i);
        acc = (p4.x - __logf(s4.x)) + (p4.y - __logf(s4.y)) +
              (p4.z - __logf(s4.z)) + (p4.w - __logf(s4.w));
    }
    #pragma unroll
    for (int off = 32; off > 0; off >>= 1) acc += __shfl_xor(acc, off);
    __shared__ float wsum[16];
    const int wave = threadIdx.x >> 6, lane = threadIdx.x & 63;
    if (lane == 0) wsum[wave] = acc;
    __syncthreads();
    if (threadIdx.x == 0) {
        float tot = 0.0f;
        #pragma unroll
        for (int w = 0; w < 16; ++w) tot += wsum[w];
        out[0] = -tot / (float)N;
    }
}

// ---------------------------------------------------------------------------
extern "C" void kernel_launch(void* const* d_in, const int* in_sizes, int n_in,
                              void* d_out, int out_size, void* d_ws, size_t ws_size,
                              hipStream_t stream) {
    const float* a = (const float*)d_in[0];
    const float* b = (const float*)d_in[1];
    float* out = (float*)d_out;
    const int N = NROWS;

    char* ws = (char*)d_ws;
    unsigned short* en = (unsigned short*)ws;                  // 2N*D*2 = 4 MB
    float* S = (float*)(ws + (size_t)2 * N * DDIM * sizeof(unsigned short));
    float* pos = S + N;

    prep_kernel<<<N / 4, 256, 0, stream>>>(a, b, en, S, pos, N);
    simsum_kernel<<<dim3(NROWS / 256, NJ), 256, 0, stream>>>((const short*)en, S);
    loss_kernel<<<1, 1024, 0, stream>>>(S, pos, out, N);
}

// Round 8
// 93.873 us; speedup vs baseline: 1.0007x; 1.0007x over previous
//
#include <hip/hip_runtime.h>
#include <hip/hip_bf16.h>

#define NROWS 4096
#define DDIM  256
#define EPS   1e-8f
// Normalized rows are scaled by sqrt(2*log2(e)) so the MFMA dot product IS the
// exp2 argument: exp2(<se_i, se_j>) = exp(<e_i,e_j>/T), T = 0.5.
#define SCALE 1.69864944f
#define LN2   0.69314718056f

#define NJ 64          // j-slices (grid.y)
#define JS 128         // cols per slice
#define NCG (JS / 16)  // 8 column-groups of 16
// LDS fragment-ordered: [cg(8)][ks(8)][lane(64)][8 shorts] = 64 KB, 1 buffer
#define LDSSH (NCG * 8 * 64 * 8)

typedef __attribute__((ext_vector_type(8))) short short8;
typedef __attribute__((ext_vector_type(4))) float f32x4;

#if __has_builtin(__builtin_amdgcn_exp2f)
#define EXP2F(x) __builtin_amdgcn_exp2f(x)
#else
#define EXP2F(x) exp2f(x)
#endif

__device__ __forceinline__ unsigned short f2bf(float x) {
    union { __hip_bfloat16 h; unsigned short u; } c;
    c.h = __float2bfloat16(x);
    return c.u;
}

__device__ __forceinline__ float bf2f(unsigned short u) {
    union { float f; unsigned int i; } c;
    c.i = ((unsigned int)u) << 16;
    return c.f;
}

// ---------------------------------------------------------------------------
// Kernel 1 (fused normalize + positive_sim): one wave owns the PAIR (i, N+i).
// grid = N/4 blocks x 256 threads.
__global__ void prep_kernel(const float* __restrict__ a,
                            const float* __restrict__ b,
                            unsigned short* __restrict__ en,
                            float* __restrict__ S,
                            float* __restrict__ pos, int N) {
    const int wave = threadIdx.x >> 6, lane = threadIdx.x & 63;
    const int row = blockIdx.x * 4 + wave;          // pair index in [0,N)
    const float4 va = reinterpret_cast<const float4*>(a + (size_t)row * DDIM)[lane];
    const float4 vb = reinterpret_cast<const float4*>(b + (size_t)row * DDIM)[lane];
    float ssa = va.x * va.x + va.y * va.y + va.z * va.z + va.w * va.w;
    float ssb = vb.x * vb.x + vb.y * vb.y + vb.z * vb.z + vb.w * vb.w;
    #pragma unroll
    for (int off = 32; off > 0; off >>= 1) {
        ssa += __shfl_xor(ssa, off);
        ssb += __shfl_xor(ssb, off);
    }
    const float inva = SCALE / fmaxf(sqrtf(ssa), EPS * SCALE);
    const float invb = SCALE / fmaxf(sqrtf(ssb), EPS * SCALE);
    ushort4 oa, ob;
    oa.x = f2bf(va.x * inva); oa.y = f2bf(va.y * inva);
    oa.z = f2bf(va.z * inva); oa.w = f2bf(va.w * inva);
    ob.x = f2bf(vb.x * invb); ob.y = f2bf(vb.y * invb);
    ob.z = f2bf(vb.z * invb); ob.w = f2bf(vb.w * invb);
    *reinterpret_cast<ushort4*>(en + (size_t)row * DDIM + lane * 4) = oa;
    *reinterpret_cast<ushort4*>(en + (size_t)(N + row) * DDIM + lane * 4) = ob;
    float d = bf2f(oa.x) * bf2f(ob.x) + bf2f(oa.y) * bf2f(ob.y) +
              bf2f(oa.z) * bf2f(ob.z) + bf2f(oa.w) * bf2f(ob.w);
    #pragma unroll
    for (int off = 32; off > 0; off >>= 1) d += __shfl_xor(d, off);
    if (lane == 0) {
        pos[row] = d * LN2;
        S[row] = 0.0f;
    }
}

// ---------------------------------------------------------------------------
// Kernel 2: masked exp row-sums via MFMA — block-churn TLP structure.
// Evidence trail: per-chunk barrier loops stall all 4 waves together (R3:
// Occ 17%, both pipes ~10%, conflicts 0); every added in-block pipeline
// mechanism spilled (R4/R5/R7: WRITE_SIZE 44-400 MB). This version adds ZERO
// register state and removes sync instead: each block stages its whole
// 128-col B-slice ONCE (64 KB LDS, single buffer), does ONE vmcnt(0) + ONE
// s_barrier, then computes 8 cg tiles with no further synchronization and
// retires (~2-3 us). 1024 blocks churn through 256 CUs; co-resident blocks
// sit in different phases (one staging while the other MFMAs), restoring the
// CU-level overlap the lockstep chunk loop prevented.
// Register shape = R3-proven no-spill allocation: 256 thr, t=4,
// __launch_bounds__(256,2) (VGPR 120, WRITE ~0.5 MB there).
// grid = (4096/256 = 16 i-blocks, NJ=64 j-slices) = 1024 blocks.
// MFMA 16x16x32 bf16 verified layouts:
//   A/B operand: elem j of lane l = M[base + (l&15)][ks*32 + (l>>4)*8 + j]
//   C/D:         reg r of lane l  = C[(l>>4)*4 + r][l&15]
__global__ __launch_bounds__(256, 2) void simsum_kernel(
        const short* __restrict__ en,
        float* __restrict__ S) {
    __shared__ short bt[LDSSH];
    const int tid = threadIdx.x;
    const int wave = tid >> 6, lane = tid & 63;
    const int lrow = lane & 15, quad = lane >> 4;
    const int i0 = blockIdx.x * 256 + wave * 64;
    const int jb = blockIdx.y * JS;

    // Stage the whole B-slice: wave w covers cgs {2w, 2w+1} -> 16 DMA each.
    // LDS dest is wave-uniform base + lane*16B == fragment order for ds_read.
    #pragma unroll
    for (int s = 0; s < 2; ++s) {
        const int cg = wave * 2 + s;
        const short* g = en + (size_t)(jb + cg * 16 + lrow) * DDIM + quad * 8;
        short* l = bt + cg * 4096;
        #pragma unroll
        for (int ks = 0; ks < 8; ++ks) {
            __builtin_amdgcn_global_load_lds(
                (const __attribute__((address_space(1))) void*)(g + ks * 32),
                (__attribute__((address_space(3))) void*)(l + ks * 512),
                16, 0, 0);
        }
    }

    // A fragments: 4 row-tiles x K=256, loaded concurrently with the DMA.
    short8 afrag[4][8];
    #pragma unroll
    for (int t = 0; t < 4; ++t)
        #pragma unroll
        for (int ks = 0; ks < 8; ++ks)
            afrag[t][ks] = *reinterpret_cast<const short8*>(
                en + (size_t)(i0 + t * 16 + lrow) * DDIM + ks * 32 + quad * 8);

    float rowsum[4][4];
    #pragma unroll
    for (int t = 0; t < 4; ++t)
        #pragma unroll
        for (int r = 0; r < 4; ++r) rowsum[t][r] = 0.0f;

    // The kernel's ONLY synchronization point.
    asm volatile("s_waitcnt vmcnt(0)" ::: "memory");
    __builtin_amdgcn_s_barrier();

    // Sync-free compute: 8 tiles of 64x16.
    #pragma unroll
    for (int cg = 0; cg < NCG; ++cg) {
        f32x4 acc[4];
        #pragma unroll
        for (int t = 0; t < 4; ++t) acc[t] = f32x4{0.f, 0.f, 0.f, 0.f};
        __builtin_amdgcn_s_setprio(1);
        #pragma unroll
        for (int ks = 0; ks < 8; ++ks) {
            const short8 bfrag = *reinterpret_cast<const short8*>(
                bt + cg * 4096 + ks * 512 + lane * 8);
            #pragma unroll
            for (int t = 0; t < 4; ++t)
                acc[t] = __builtin_amdgcn_mfma_f32_16x16x32_bf16(
                    afrag[t][ks], bfrag, acc[t], 0, 0, 0);
        }
        __builtin_amdgcn_s_setprio(0);
        // Branch-free epilogue: exclude the (at most one) diagonal-family
        // element per lane via compare+select (j%N == i%N).
        const int cm = (jb + cg * 16 + lrow) & (NROWS - 1);
        #pragma unroll
        for (int t = 0; t < 4; ++t) {
            const int dd = cm - (i0 + t * 16 + quad * 4);  // match when dd==r
            #pragma unroll
            for (int r = 0; r < 4; ++r) {
                const float ed = EXP2F(acc[t][r]);
                rowsum[t][r] += (dd == r) ? 0.0f : ed;
            }
        }
    }

    // Reduce each rowsum over the 16 lanes sharing a quad, then one atomic.
    #pragma unroll
    for (int t = 0; t < 4; ++t) {
        #pragma unroll
        for (int r = 0; r < 4; ++r) {
            float v = rowsum[t][r];
            v += __shfl_xor(v, 1);
            v += __shfl_xor(v, 2);
            v += __shfl_xor(v, 4);
            v += __shfl_xor(v, 8);
            rowsum[t][r] = v;
        }
        if (lrow < 4) {
            const float v = (lrow == 0) ? rowsum[t][0]
                          : (lrow == 1) ? rowsum[t][1]
                          : (lrow == 2) ? rowsum[t][2]
                          :               rowsum[t][3];
            atomicAdd(&S[i0 + t * 16 + quad * 4 + lrow], v);
        }
    }
}

// ---------------------------------------------------------------------------
// Kernel 3: loss = -(1/N) * sum_i (pos[i] - log(S[i])). One block x 1024.
__global__ void loss_kernel(const float* __restrict__ S,
                            const float* __restrict__ pos,
                            float* __restrict__ out, int N) {
    const int i = threadIdx.x * 4;
    float acc = 0.0f;
    if (i < N) {
        const float4 s4 = *reinterpret_cast<const float4*>(S + i);
        const float4 p4 = *reinterpret_cast<const float4*>(pos + i);
        acc = (p4.x - __logf(s4.x)) + (p4.y - __logf(s4.y)) +
              (p4.z - __logf(s4.z)) + (p4.w - __logf(s4.w));
    }
    #pragma unroll
    for (int off = 32; off > 0; off >>= 1) acc += __shfl_xor(acc, off);
    __shared__ float wsum[16];
    const int wave = threadIdx.x >> 6, lane = threadIdx.x & 63;
    if (lane == 0) wsum[wave] = acc;
    __syncthreads();
    if (threadIdx.x == 0) {
        float tot = 0.0f;
        #pragma unroll
        for (int w = 0; w < 16; ++w) tot += wsum[w];
        out[0] = -tot / (float)N;
    }
}

// ---------------------------------------------------------------------------
extern "C" void kernel_launch(void* const* d_in, const int* in_sizes, int n_in,
                              void* d_out, int out_size, void* d_ws, size_t ws_size,
                              hipStream_t stream) {
    const float* a = (const float*)d_in[0];
    const float* b = (const float*)d_in[1];
    float* out = (float*)d_out;
    const int N = NROWS;

    char* ws = (char*)d_ws;
    unsigned short* en = (unsigned short*)ws;                  // 2N*D*2 = 4 MB
    float* S = (float*)(ws + (size_t)2 * N * DDIM * sizeof(unsigned short));
    float* pos = S + N;

    prep_kernel<<<N / 4, 256, 0, stream>>>(a, b, en, S, pos, N);
    simsum_kernel<<<dim3(NROWS / 256, NJ), 256, 0, stream>>>((const short*)en, S);
    loss_kernel<<<1, 1024, 0, stream>>>(S, pos, out, N);
}